// Round 1
// baseline (548.757 us; speedup 1.0000x reference)
//
#include <hip/hip_runtime.h>
#include <hip/hip_bf16.h>

#define S_DIM 4096
#define D_DIM 1024
#define F_DIM 4096

typedef unsigned short ushort_t;
typedef __attribute__((ext_vector_type(8))) short sh8;
typedef __attribute__((ext_vector_type(4))) short sh4;
typedef __attribute__((ext_vector_type(4))) float fx4;

__device__ __forceinline__ ushort_t f2bf(float f) {
    union { float f; unsigned u; } v; v.f = f;
    unsigned r = v.u + 0x7fffu + ((v.u >> 16) & 1u);
    return (ushort_t)(r >> 16);
}
__device__ __forceinline__ float bf2f(ushort_t u) {
    union { unsigned u; float f; } v; v.u = ((unsigned)u) << 16;
    return v.f;
}

typedef const __attribute__((address_space(1))) void* gvp;
typedef __attribute__((address_space(3))) void* svp;
__device__ __forceinline__ void gload_lds16(const void* g, void* l) {
    __builtin_amdgcn_global_load_lds((gvp)g, (svp)l, 16, 0, 0);
}

// ---------------------------------------------------------------------------
// bf16 GEMM: C[M,N] = A[M,K] @ B[K,N] (+bias) where Bt[N,K] = B^T supplied.
// 128x128 tile, BK=32, 256 threads (4 waves, 2x2), mfma_f32_16x16x32_bf16.
// ---------------------------------------------------------------------------
#define BM 128
#define BN 128
#define BK 32

template<bool BIAS, bool RELU, bool MASK, bool OUTBF>
__global__ __launch_bounds__(256)
void gemm_bt(const ushort_t* __restrict__ A, const ushort_t* __restrict__ Bt,
             const float* __restrict__ bias, const float* __restrict__ mask,
             float* __restrict__ Cf, ushort_t* __restrict__ Cb,
             int M, int N, int K, float scale)
{
    __shared__ ushort_t lds[BM * BK + BN * BK];   // 16 KiB
    const int tid = threadIdx.x;
    const int bm = blockIdx.x, bn = blockIdx.y;
    const int w  = tid >> 6, l = tid & 63;
    const int wm = w >> 1, wn = w & 1;

    fx4 acc[4][4] = {};

    const ushort_t* Ag = A  + (size_t)(bm * BM) * K;
    const ushort_t* Bg = Bt + (size_t)(bn * BN) * K;
    char* lbase = (char*)lds;

    for (int k0 = 0; k0 < K; k0 += BK) {
        __syncthreads();   // prior iteration's reads done before overwrite
        #pragma unroll
        for (int c = 0; c < 2; ++c) {
            int gi  = c * 256 + tid;     // 16B granule index
            int row = gi >> 2;
            int cs  = gi & 3;
            gload_lds16(Ag + (size_t)row * K + k0 + cs * 8,
                        lbase + c * 4096 + tid * 16);
            gload_lds16(Bg + (size_t)row * K + k0 + cs * 8,
                        lbase + 8192 + c * 4096 + tid * 16);
        }
        __syncthreads();   // compiler inserts vmcnt(0) drain here

        sh8 af[4], bfr[4];
        #pragma unroll
        for (int t = 0; t < 4; ++t) {
            int ra = wm * 64 + t * 16 + (l & 15);
            af[t]  = *(const sh8*)(lbase + ra * 64 + (l >> 4) * 16);
            int rb = wn * 64 + t * 16 + (l & 15);
            bfr[t] = *(const sh8*)(lbase + 8192 + rb * 64 + (l >> 4) * 16);
        }
        #pragma unroll
        for (int i = 0; i < 4; ++i)
            #pragma unroll
            for (int j = 0; j < 4; ++j)
                acc[i][j] = __builtin_amdgcn_mfma_f32_16x16x32_bf16(
                                af[i], bfr[j], acc[i][j], 0, 0, 0);
    }

    const int crow0 = bm * BM + wm * 64;
    const int ccol0 = bn * BN + wn * 64;
    #pragma unroll
    for (int i = 0; i < 4; ++i) {
        #pragma unroll
        for (int j = 0; j < 4; ++j) {
            int col = ccol0 + j * 16 + (l & 15);
            float bia = BIAS ? bias[col] : 0.f;
            #pragma unroll
            for (int r = 0; r < 4; ++r) {
                int row = crow0 + i * 16 + (l >> 4) * 4 + r;
                float v = acc[i][j][r] + bia;
                if (MASK) v = v * mask[(size_t)row * N + col] * scale;
                if (RELU) v = fmaxf(v, 0.f);
                if (OUTBF) Cb[(size_t)row * N + col] = f2bf(v);
                else       Cf[(size_t)row * N + col] = v;
            }
        }
    }
}

// ---------------------------------------------------------------------------
// fp32 [R][C] -> bf16 [C][R] transpose (32x32 LDS tiles, padded)
// ---------------------------------------------------------------------------
__global__ __launch_bounds__(256)
void transpose_f32_bf16(const float* __restrict__ in, ushort_t* __restrict__ out,
                        int R, int C)
{
    __shared__ float t[32][33];
    int bc = blockIdx.x * 32, br = blockIdx.y * 32;
    int tx = threadIdx.x & 31, ty = threadIdx.x >> 5;
    #pragma unroll
    for (int i = 0; i < 32; i += 8)
        t[ty + i][tx] = in[(size_t)(br + ty + i) * C + bc + tx];
    __syncthreads();
    #pragma unroll
    for (int i = 0; i < 32; i += 8)
        out[(size_t)(bc + ty + i) * R + br + tx] = f2bf(t[tx][ty + i]);
}

// fp32 -> bf16 elementwise (8 / thread)
__global__ __launch_bounds__(256)
void cvt_bf16(const float* __restrict__ in, ushort_t* __restrict__ out, int n)
{
    int i = (blockIdx.x * 256 + threadIdx.x) * 8;
    if (i < n) {
        const float4* p = (const float4*)(in + i);
        float4 a = p[0], b = p[1];
        sh8 r;
        r[0] = (short)f2bf(a.x); r[1] = (short)f2bf(a.y);
        r[2] = (short)f2bf(a.z); r[3] = (short)f2bf(a.w);
        r[4] = (short)f2bf(b.x); r[5] = (short)f2bf(b.y);
        r[6] = (short)f2bf(b.z); r[7] = (short)f2bf(b.w);
        *(sh8*)(out + i) = r;
    }
}

// ---------------------------------------------------------------------------
// Column softmax (axis 0) over masked-scaled scores m[S][S] (bf16), 3 passes
// ---------------------------------------------------------------------------
#define SM_CH 32

__global__ __launch_bounds__(256)
void smax_pass1(const ushort_t* __restrict__ m, float* __restrict__ pmax,
                float* __restrict__ psum)
{
    int col = blockIdx.x * 256 + threadIdx.x;
    int chunk = blockIdx.y;
    int r0 = chunk * (S_DIM / SM_CH);
    float mx = -1e30f, sm = 0.f;
    for (int i = 0; i < S_DIM / SM_CH; ++i) {
        float v = bf2f(m[(size_t)(r0 + i) * S_DIM + col]);
        if (v > mx) { sm = sm * __expf(mx - v) + 1.f; mx = v; }
        else        { sm += __expf(v - mx); }
    }
    pmax[chunk * S_DIM + col] = mx;
    psum[chunk * S_DIM + col] = sm;
}

__global__ __launch_bounds__(256)
void smax_pass2(const float* __restrict__ pmax, const float* __restrict__ psum,
                float* __restrict__ cmax, float* __restrict__ cinv)
{
    int col = blockIdx.x * 256 + threadIdx.x;
    float mx = -1e30f, sm = 0.f;
    for (int c = 0; c < SM_CH; ++c) {
        float m2 = pmax[c * S_DIM + col];
        float s2 = psum[c * S_DIM + col];
        if (m2 > mx) { sm = sm * __expf(mx - m2) + s2; mx = m2; }
        else         { sm += s2 * __expf(m2 - mx); }
    }
    cmax[col] = mx;
    cinv[col] = 1.f / sm;
}

__global__ __launch_bounds__(256)
void smax_pass3(const ushort_t* __restrict__ m, const float* __restrict__ cmax,
                const float* __restrict__ cinv, ushort_t* __restrict__ h)
{
    size_t idx = ((size_t)blockIdx.x * 256 + threadIdx.x) * 8;
    int col0 = (int)(idx & (S_DIM - 1));
    sh8 mv = *(const sh8*)(m + idx);
    sh8 r;
    #pragma unroll
    for (int j = 0; j < 8; ++j) {
        int c = col0 + j;
        float v = bf2f((ushort_t)mv[j]);
        r[j] = (short)f2bf(__expf(v - cmax[c]) * cinv[c]);
    }
    *(sh8*)(h + idx) = r;
}

// ---------------------------------------------------------------------------
// LayerNorm(a + b) over D=1024, one row per block (256 thr x 4 elem)
// ---------------------------------------------------------------------------
template<bool WF, bool WB>
__global__ __launch_bounds__(256)
void add_ln(const float* __restrict__ a, const float* __restrict__ b,
            const float* __restrict__ g, const float* __restrict__ be,
            float* __restrict__ of, ushort_t* __restrict__ ob)
{
    const int D = D_DIM;
    int row = blockIdx.x, tid = threadIdx.x;
    float4 va = ((const float4*)(a + (size_t)row * D))[tid];
    float4 vb = ((const float4*)(b + (size_t)row * D))[tid];
    float x0 = va.x + vb.x, x1 = va.y + vb.y, x2 = va.z + vb.z, x3 = va.w + vb.w;
    float s = x0 + x1 + x2 + x3;
    float q = x0 * x0 + x1 * x1 + x2 * x2 + x3 * x3;
    #pragma unroll
    for (int off = 32; off; off >>= 1) {
        s += __shfl_down(s, off);
        q += __shfl_down(q, off);
    }
    __shared__ float red[8];
    int w = tid >> 6, l = tid & 63;
    if (!l) { red[w] = s; red[4 + w] = q; }
    __syncthreads();
    s = red[0] + red[1] + red[2] + red[3];
    q = red[4] + red[5] + red[6] + red[7];
    float mu = s * (1.f / D);
    float rstd = rsqrtf(q * (1.f / D) - mu * mu + 1e-5f);
    float4 vg  = ((const float4*)g)[tid];
    float4 vbe = ((const float4*)be)[tid];
    float y0 = (x0 - mu) * rstd * vg.x + vbe.x;
    float y1 = (x1 - mu) * rstd * vg.y + vbe.y;
    float y2 = (x2 - mu) * rstd * vg.z + vbe.z;
    float y3 = (x3 - mu) * rstd * vg.w + vbe.w;
    if (WF) {
        float4 r; r.x = y0; r.y = y1; r.z = y2; r.w = y3;
        ((float4*)(of + (size_t)row * D))[tid] = r;
    }
    if (WB) {
        sh4 rb;
        rb[0] = (short)f2bf(y0); rb[1] = (short)f2bf(y1);
        rb[2] = (short)f2bf(y2); rb[3] = (short)f2bf(y3);
        *(sh4*)(ob + (size_t)row * D + tid * 4) = rb;
    }
}

// ---------------------------------------------------------------------------
extern "C" void kernel_launch(void* const* d_in, const int* in_sizes, int n_in,
                              void* d_out, int out_size, void* d_ws, size_t ws_size,
                              hipStream_t stream)
{
    const float* query = (const float*)d_in[0];
    const float* key_  = (const float*)d_in[1];
    const float* value = (const float*)d_in[2];
    const float* mask  = (const float*)d_in[3];
    const float* Wq = (const float*)d_in[4];  const float* bq = (const float*)d_in[5];
    const float* Wk = (const float*)d_in[6];  const float* bk = (const float*)d_in[7];
    const float* Wv = (const float*)d_in[8];  const float* bv = (const float*)d_in[9];
    const float* Wo = (const float*)d_in[10]; const float* bo = (const float*)d_in[11];
    const float* g1 = (const float*)d_in[12]; const float* be1 = (const float*)d_in[13];
    const float* W1 = (const float*)d_in[14]; const float* bf1 = (const float*)d_in[15];
    const float* W2 = (const float*)d_in[16]; const float* bf2 = (const float*)d_in[17];
    const float* g2 = (const float*)d_in[18]; const float* be2 = (const float*)d_in[19];

    const size_t MB = 1ull << 20;
    char* ws = (char*)d_ws;
    ushort_t* WqT = (ushort_t*)(ws);
    ushort_t* WkT = (ushort_t*)(ws + 2 * MB);
    ushort_t* WvT = (ushort_t*)(ws + 4 * MB);
    ushort_t* WoT = (ushort_t*)(ws + 6 * MB);
    ushort_t* W1T = (ushort_t*)(ws + 8 * MB);    // [F][D]
    ushort_t* W2T = (ushort_t*)(ws + 16 * MB);   // [D][F]
    ushort_t* qin = (ushort_t*)(ws + 24 * MB);
    ushort_t* kin = (ushort_t*)(ws + 32 * MB);
    ushort_t* vin = (ushort_t*)(ws + 40 * MB);
    ushort_t* qb  = (ushort_t*)(ws + 48 * MB);
    ushort_t* kb  = (ushort_t*)(ws + 56 * MB);
    float*    vtmp= (float*)   (ws + 64 * MB);   // [S][D] fp32
    ushort_t* vT  = (ushort_t*)(ws + 80 * MB);   // [D][S]
    ushort_t* msc = (ushort_t*)(ws + 88 * MB);   // masked scaled scores bf16 [S][S]
    ushort_t* hb  = (ushort_t*)(ws + 120 * MB);  // softmax bf16 [S][S]
    float*   pmax = (float*)(ws + 152 * MB);
    float*   psum = (float*)(ws + 152 * MB + 512 * 1024);
    float*   cmax = (float*)(ws + 153 * MB);
    float*   cinv = (float*)(ws + 153 * MB + 64 * 1024);
    // aliased (dead-buffer reuse)
    ushort_t* apb   = qin;                       // attn_pre bf16 [S][D]
    float*    attnf = (float*)(ws + 48 * MB);    // attn+bo fp32 [S][D] (over qb/kb? no: see below)
    // careful: attnf computed while qb,kb already dead; put over kin/vin region
    attnf = (float*)(ws + 32 * MB);              // [32,48) over kin+vin
    float*    n1f = (float*)(ws + 48 * MB);      // over qb,kb
    ushort_t* n1b = (ushort_t*)(ws + 64 * MB);   // over vtmp
    ushort_t* mid = (ushort_t*)(ws + 88 * MB);   // over msc  [S][F] bf16
    float*    ff  = (float*)(ws + 120 * MB);     // over hb   [S][D] fp32

    const int S = S_DIM, D = D_DIM, F = F_DIM;

    // 1. weights -> bf16 transposed
    transpose_f32_bf16<<<dim3(D / 32, D / 32), 256, 0, stream>>>(Wq, WqT, D, D);
    transpose_f32_bf16<<<dim3(D / 32, D / 32), 256, 0, stream>>>(Wk, WkT, D, D);
    transpose_f32_bf16<<<dim3(D / 32, D / 32), 256, 0, stream>>>(Wv, WvT, D, D);
    transpose_f32_bf16<<<dim3(D / 32, D / 32), 256, 0, stream>>>(Wo, WoT, D, D);
    transpose_f32_bf16<<<dim3(F / 32, D / 32), 256, 0, stream>>>(W1, W1T, D, F);
    transpose_f32_bf16<<<dim3(D / 32, F / 32), 256, 0, stream>>>(W2, W2T, F, D);

    // 2. activations -> bf16
    cvt_bf16<<<(S * D / 8 + 255) / 256, 256, 0, stream>>>(query, qin, S * D);
    cvt_bf16<<<(S * D / 8 + 255) / 256, 256, 0, stream>>>(key_,  kin, S * D);
    cvt_bf16<<<(S * D / 8 + 255) / 256, 256, 0, stream>>>(value, vin, S * D);

    // 3. q,k (bf16 out), v (fp32 out for transpose)
    gemm_bt<true, false, false, true><<<dim3(S / BM, D / BN), 256, 0, stream>>>(
        qin, WqT, bq, nullptr, nullptr, qb, S, D, D, 1.f);
    gemm_bt<true, false, false, true><<<dim3(S / BM, D / BN), 256, 0, stream>>>(
        kin, WkT, bk, nullptr, nullptr, kb, S, D, D, 1.f);
    gemm_bt<true, false, false, false><<<dim3(S / BM, D / BN), 256, 0, stream>>>(
        vin, WvT, bv, nullptr, vtmp, nullptr, S, D, D, 1.f);

    // 4. v^T bf16 [D][S]
    transpose_f32_bf16<<<dim3(D / 32, S / 32), 256, 0, stream>>>(vtmp, vT, S, D);

    // 5. masked scaled scores bf16: (q @ k^T) * mask / sqrt(D)
    gemm_bt<false, false, true, true><<<dim3(S / BM, S / BN), 256, 0, stream>>>(
        qb, kb, nullptr, mask, nullptr, msc, S, S, D, 0.03125f);

    // 6. column softmax
    smax_pass1<<<dim3(S / 256, SM_CH), 256, 0, stream>>>(msc, pmax, psum);
    smax_pass2<<<S / 256, 256, 0, stream>>>(pmax, psum, cmax, cinv);
    smax_pass3<<<(size_t)S * S / 8 / 256, 256, 0, stream>>>(msc, cmax, cinv, hb);

    // 7. attn_pre = h @ v
    gemm_bt<false, false, false, true><<<dim3(S / BM, D / BN), 256, 0, stream>>>(
        hb, vT, nullptr, nullptr, nullptr, apb, S, D, S, 1.f);

    // 8. attn = attn_pre @ Wo + bo (fp32)
    gemm_bt<true, false, false, false><<<dim3(S / BM, D / BN), 256, 0, stream>>>(
        apb, WoT, bo, nullptr, attnf, nullptr, S, D, D, 1.f);

    // 9. n1 = LN(attn + query)
    add_ln<true, true><<<S, 256, 0, stream>>>(attnf, query, g1, be1, n1f, n1b);

    // 10. mid = relu(n1 @ W1 + bf1) bf16
    gemm_bt<true, true, false, true><<<dim3(S / BM, F / BN), 256, 0, stream>>>(
        n1b, W1T, bf1, nullptr, nullptr, mid, S, F, D, 1.f);

    // 11. ff = mid @ W2 + bf2 (fp32)
    gemm_bt<true, false, false, false><<<dim3(S / BM, D / BN), 256, 0, stream>>>(
        mid, W2T, bf2, nullptr, ff, nullptr, S, D, F, 1.f);

    // 12. out = LN(ff + n1)
    add_ln<true, false><<<S, 256, 0, stream>>>(ff, n1f, g2, be2, (float*)d_out, nullptr);
}

// Round 2
// 455.183 us; speedup vs baseline: 1.2056x; 1.2056x over previous
//
#include <hip/hip_runtime.h>
#include <hip/hip_bf16.h>

#define S_DIM 4096
#define D_DIM 1024
#define F_DIM 4096

typedef unsigned short ushort_t;
typedef __attribute__((ext_vector_type(8))) short sh8;
typedef __attribute__((ext_vector_type(4))) short sh4;
typedef __attribute__((ext_vector_type(4))) float fx4;

__device__ __forceinline__ ushort_t f2bf(float f) {
    union { float f; unsigned u; } v; v.f = f;
    unsigned r = v.u + 0x7fffu + ((v.u >> 16) & 1u);
    return (ushort_t)(r >> 16);
}
__device__ __forceinline__ float bf2f(ushort_t u) {
    union { unsigned u; float f; } v; v.u = ((unsigned)u) << 16;
    return v.f;
}

typedef const __attribute__((address_space(1))) void* gvp;
typedef __attribute__((address_space(3))) void* svp;
__device__ __forceinline__ void gload_lds16(const void* g, void* l) {
    __builtin_amdgcn_global_load_lds((gvp)g, (svp)l, 16, 0, 0);
}

// ---------------------------------------------------------------------------
// bf16 GEMM body: C[M,N] = A[M,K] @ B[K,N] (+bias) with Bt[N,K] = B^T.
// 128x128 tile, BK=32, 256 threads (4 waves 2x2), mfma_f32_16x16x32_bf16.
// K-range [kBeg,kEnd) for split-K; SPLITK writes bf16 partial at z*M*N.
// ---------------------------------------------------------------------------
#define BM 128
#define BN 128
#define BK 32

template<bool BIAS, bool RELU, bool MASK, bool OUTBF, bool SPLITK>
__device__ __forceinline__
void gemm_body(const ushort_t* A, const ushort_t* Bt,
               const float* bias, const float* mask,
               float* Cf, ushort_t* Cb,
               int M, int N, int K, int kBeg, int kEnd, float scale)
{
    __shared__ ushort_t lds[BM * BK + BN * BK];   // 16 KiB
    const int tid = threadIdx.x;
    const int bm = blockIdx.x, bn = blockIdx.y;
    const int w  = tid >> 6, l = tid & 63;
    const int wm = w >> 1, wn = w & 1;

    fx4 acc[4][4] = {};

    const ushort_t* Ag = A  + (size_t)(bm * BM) * K;
    const ushort_t* Bg = Bt + (size_t)(bn * BN) * K;
    char* lbase = (char*)lds;

    for (int k0 = kBeg; k0 < kEnd; k0 += BK) {
        __syncthreads();
        #pragma unroll
        for (int c = 0; c < 2; ++c) {
            int gi  = c * 256 + tid;     // 16B granule index
            int row = gi >> 2;
            int cs  = gi & 3;
            gload_lds16(Ag + (size_t)row * K + k0 + cs * 8,
                        lbase + c * 4096 + tid * 16);
            gload_lds16(Bg + (size_t)row * K + k0 + cs * 8,
                        lbase + 8192 + c * 4096 + tid * 16);
        }
        __syncthreads();

        sh8 af[4], bfr[4];
        #pragma unroll
        for (int t = 0; t < 4; ++t) {
            int ra = wm * 64 + t * 16 + (l & 15);
            af[t]  = *(const sh8*)(lbase + ra * 64 + (l >> 4) * 16);
            int rb = wn * 64 + t * 16 + (l & 15);
            bfr[t] = *(const sh8*)(lbase + 8192 + rb * 64 + (l >> 4) * 16);
        }
        #pragma unroll
        for (int i = 0; i < 4; ++i)
            #pragma unroll
            for (int j = 0; j < 4; ++j)
                acc[i][j] = __builtin_amdgcn_mfma_f32_16x16x32_bf16(
                                af[i], bfr[j], acc[i][j], 0, 0, 0);
    }

    if (SPLITK) Cb += (size_t)blockIdx.z * M * N;

    const int crow0 = bm * BM + wm * 64;
    const int ccol0 = bn * BN + wn * 64;
    #pragma unroll
    for (int i = 0; i < 4; ++i) {
        #pragma unroll
        for (int j = 0; j < 4; ++j) {
            int col = ccol0 + j * 16 + (l & 15);
            float bia = BIAS ? bias[col] : 0.f;
            #pragma unroll
            for (int r = 0; r < 4; ++r) {
                int row = crow0 + i * 16 + (l >> 4) * 4 + r;
                float v = acc[i][j][r] + bia;
                if (MASK) v = v * mask[(size_t)row * N + col] * scale;
                if (RELU) v = fmaxf(v, 0.f);
                if (OUTBF) Cb[(size_t)row * N + col] = f2bf(v);
                else       Cf[(size_t)row * N + col] = v;
            }
        }
    }
}

template<bool BIAS, bool RELU, bool MASK, bool OUTBF>
__global__ __launch_bounds__(256)
void gemm_bt(const ushort_t* __restrict__ A, const ushort_t* __restrict__ Bt,
             const float* __restrict__ bias, const float* __restrict__ mask,
             float* __restrict__ Cf, ushort_t* __restrict__ Cb,
             int M, int N, int K, float scale)
{
    gemm_body<BIAS, RELU, MASK, OUTBF, false>(A, Bt, bias, mask, Cf, Cb,
                                              M, N, K, 0, K, scale);
}

// split-K: blockIdx.z = K-slice, bf16 partial per slice
__global__ __launch_bounds__(256)
void gemm_bt_sk(const ushort_t* __restrict__ A, const ushort_t* __restrict__ Bt,
                ushort_t* __restrict__ Cpart, int M, int N, int K, int Ks)
{
    int z = blockIdx.z;
    gemm_body<false, false, false, true, true>(A, Bt, nullptr, nullptr,
                                               nullptr, Cpart,
                                               M, N, K, z * Ks, z * Ks + Ks, 1.f);
}

// batched q/k/v projection: blockIdx.z selects operand set
__global__ __launch_bounds__(256)
void qkv_gemm(const ushort_t* qin, const ushort_t* kin, const ushort_t* vin,
              const ushort_t* WqT, const ushort_t* WkT, const ushort_t* WvT,
              const float* bq, const float* bk, const float* bv,
              ushort_t* qb, ushort_t* kb, ushort_t* vb, int M, int N, int K)
{
    const ushort_t* A; const ushort_t* Bt; const float* bias; ushort_t* C;
    if (blockIdx.z == 0)      { A = qin; Bt = WqT; bias = bq; C = qb; }
    else if (blockIdx.z == 1) { A = kin; Bt = WkT; bias = bk; C = kb; }
    else                      { A = vin; Bt = WvT; bias = bv; C = vb; }
    gemm_body<true, false, false, true, false>(A, Bt, bias, nullptr,
                                               nullptr, C, M, N, K, 0, K, 1.f);
}

// sum NS bf16 partial matrices (+bias), write f32 or bf16
template<int NS, bool BIAS, bool OUTBF>
__global__ __launch_bounds__(256)
void reduce_sk(const ushort_t* __restrict__ parts, const float* __restrict__ bias,
               float* __restrict__ of, ushort_t* __restrict__ ob,
               size_t MN, int N)
{
    size_t idx = ((size_t)blockIdx.x * 256 + threadIdx.x) * 8;
    float s[8] = {0.f, 0.f, 0.f, 0.f, 0.f, 0.f, 0.f, 0.f};
    #pragma unroll
    for (int p = 0; p < NS; ++p) {
        sh8 v = *(const sh8*)(parts + (size_t)p * MN + idx);
        #pragma unroll
        for (int j = 0; j < 8; ++j) s[j] += bf2f((ushort_t)v[j]);
    }
    if (BIAS) {
        int col0 = (int)(idx & (size_t)(N - 1));
        #pragma unroll
        for (int j = 0; j < 8; ++j) s[j] += bias[col0 + j];
    }
    if (OUTBF) {
        sh8 r;
        #pragma unroll
        for (int j = 0; j < 8; ++j) r[j] = (short)f2bf(s[j]);
        *(sh8*)(ob + idx) = r;
    } else {
        float4 r0, r1;
        r0.x = s[0]; r0.y = s[1]; r0.z = s[2]; r0.w = s[3];
        r1.x = s[4]; r1.y = s[5]; r1.z = s[6]; r1.w = s[7];
        ((float4*)(of + idx))[0] = r0;
        ((float4*)(of + idx))[1] = r1;
    }
}

// ---------------------------------------------------------------------------
// fp32 [R][C] -> bf16 [C][R] transpose
// ---------------------------------------------------------------------------
__global__ __launch_bounds__(256)
void transpose_f32_bf16(const float* __restrict__ in, ushort_t* __restrict__ out,
                        int R, int C)
{
    __shared__ float t[32][33];
    int bc = blockIdx.x * 32, br = blockIdx.y * 32;
    int tx = threadIdx.x & 31, ty = threadIdx.x >> 5;
    #pragma unroll
    for (int i = 0; i < 32; i += 8)
        t[ty + i][tx] = in[(size_t)(br + ty + i) * C + bc + tx];
    __syncthreads();
    #pragma unroll
    for (int i = 0; i < 32; i += 8)
        out[(size_t)(bc + ty + i) * R + br + tx] = f2bf(t[tx][ty + i]);
}

// bf16 [R][C] -> bf16 [C][R] transpose
__global__ __launch_bounds__(256)
void transpose_bf16(const ushort_t* __restrict__ in, ushort_t* __restrict__ out,
                    int R, int C)
{
    __shared__ ushort_t t[32][33];
    int bc = blockIdx.x * 32, br = blockIdx.y * 32;
    int tx = threadIdx.x & 31, ty = threadIdx.x >> 5;
    #pragma unroll
    for (int i = 0; i < 32; i += 8)
        t[ty + i][tx] = in[(size_t)(br + ty + i) * C + bc + tx];
    __syncthreads();
    #pragma unroll
    for (int i = 0; i < 32; i += 8)
        out[(size_t)(bc + ty + i) * R + br + tx] = t[tx][ty + i];
}

// fp32 -> bf16 elementwise (8 / thread)
__global__ __launch_bounds__(256)
void cvt_bf16(const float* __restrict__ in, ushort_t* __restrict__ out, int n)
{
    int i = (blockIdx.x * 256 + threadIdx.x) * 8;
    if (i < n) {
        const float4* p = (const float4*)(in + i);
        float4 a = p[0], b = p[1];
        sh8 r;
        r[0] = (short)f2bf(a.x); r[1] = (short)f2bf(a.y);
        r[2] = (short)f2bf(a.z); r[3] = (short)f2bf(a.w);
        r[4] = (short)f2bf(b.x); r[5] = (short)f2bf(b.y);
        r[6] = (short)f2bf(b.z); r[7] = (short)f2bf(b.w);
        *(sh8*)(out + i) = r;
    }
}

// ---------------------------------------------------------------------------
// Column softmax (axis 0) over masked-scaled scores m[S][S] (bf16)
// ---------------------------------------------------------------------------
#define SM_CH 32

__global__ __launch_bounds__(256)
void smax_pass1(const ushort_t* __restrict__ m, float* __restrict__ pmax,
                float* __restrict__ psum)
{
    int col = blockIdx.x * 256 + threadIdx.x;
    int chunk = blockIdx.y;
    int r0 = chunk * (S_DIM / SM_CH);
    float mx = -1e30f, sm = 0.f;
    for (int i = 0; i < S_DIM / SM_CH; ++i) {
        float v = bf2f(m[(size_t)(r0 + i) * S_DIM + col]);
        if (v > mx) { sm = sm * __expf(mx - v) + 1.f; mx = v; }
        else        { sm += __expf(v - mx); }
    }
    pmax[chunk * S_DIM + col] = mx;
    psum[chunk * S_DIM + col] = sm;
}

__global__ __launch_bounds__(256)
void smax_pass2(const float* __restrict__ pmax, const float* __restrict__ psum,
                float* __restrict__ cmax, float* __restrict__ cinv)
{
    int col = blockIdx.x * 256 + threadIdx.x;
    float mx = -1e30f, sm = 0.f;
    for (int c = 0; c < SM_CH; ++c) {
        float m2 = pmax[c * S_DIM + col];
        float s2 = psum[c * S_DIM + col];
        if (m2 > mx) { sm = sm * __expf(mx - m2) + s2; mx = m2; }
        else         { sm += s2 * __expf(m2 - mx); }
    }
    cmax[col] = mx;
    cinv[col] = 1.f / sm;
}

__global__ __launch_bounds__(256)
void smax_pass3(const ushort_t* __restrict__ m, const float* __restrict__ cmax,
                const float* __restrict__ cinv, ushort_t* __restrict__ h)
{
    size_t idx = ((size_t)blockIdx.x * 256 + threadIdx.x) * 8;
    int col0 = (int)(idx & (S_DIM - 1));
    sh8 mv = *(const sh8*)(m + idx);
    sh8 r;
    #pragma unroll
    for (int j = 0; j < 8; ++j) {
        int c = col0 + j;
        float v = bf2f((ushort_t)mv[j]);
        r[j] = (short)f2bf(__expf(v - cmax[c]) * cinv[c]);
    }
    *(sh8*)(h + idx) = r;
}

// ---------------------------------------------------------------------------
// LayerNorm(a + b) over D=1024, one row per block
// ---------------------------------------------------------------------------
template<bool WF, bool WB>
__global__ __launch_bounds__(256)
void add_ln(const float* __restrict__ a, const float* __restrict__ b,
            const float* __restrict__ g, const float* __restrict__ be,
            float* __restrict__ of, ushort_t* __restrict__ ob)
{
    const int D = D_DIM;
    int row = blockIdx.x, tid = threadIdx.x;
    float4 va = ((const float4*)(a + (size_t)row * D))[tid];
    float4 vb = ((const float4*)(b + (size_t)row * D))[tid];
    float x0 = va.x + vb.x, x1 = va.y + vb.y, x2 = va.z + vb.z, x3 = va.w + vb.w;
    float s = x0 + x1 + x2 + x3;
    float q = x0 * x0 + x1 * x1 + x2 * x2 + x3 * x3;
    #pragma unroll
    for (int off = 32; off; off >>= 1) {
        s += __shfl_down(s, off);
        q += __shfl_down(q, off);
    }
    __shared__ float red[8];
    int w = tid >> 6, l = tid & 63;
    if (!l) { red[w] = s; red[4 + w] = q; }
    __syncthreads();
    s = red[0] + red[1] + red[2] + red[3];
    q = red[4] + red[5] + red[6] + red[7];
    float mu = s * (1.f / D);
    float rstd = rsqrtf(q * (1.f / D) - mu * mu + 1e-5f);
    float4 vg  = ((const float4*)g)[tid];
    float4 vbe = ((const float4*)be)[tid];
    float y0 = (x0 - mu) * rstd * vg.x + vbe.x;
    float y1 = (x1 - mu) * rstd * vg.y + vbe.y;
    float y2 = (x2 - mu) * rstd * vg.z + vbe.z;
    float y3 = (x3 - mu) * rstd * vg.w + vbe.w;
    if (WF) {
        float4 r; r.x = y0; r.y = y1; r.z = y2; r.w = y3;
        ((float4*)(of + (size_t)row * D))[tid] = r;
    }
    if (WB) {
        sh4 rb;
        rb[0] = (short)f2bf(y0); rb[1] = (short)f2bf(y1);
        rb[2] = (short)f2bf(y2); rb[3] = (short)f2bf(y3);
        *(sh4*)(ob + (size_t)row * D + tid * 4) = rb;
    }
}

// ---------------------------------------------------------------------------
extern "C" void kernel_launch(void* const* d_in, const int* in_sizes, int n_in,
                              void* d_out, int out_size, void* d_ws, size_t ws_size,
                              hipStream_t stream)
{
    const float* query = (const float*)d_in[0];
    const float* key_  = (const float*)d_in[1];
    const float* value = (const float*)d_in[2];
    const float* mask  = (const float*)d_in[3];
    const float* Wq = (const float*)d_in[4];  const float* bq = (const float*)d_in[5];
    const float* Wk = (const float*)d_in[6];  const float* bk = (const float*)d_in[7];
    const float* Wv = (const float*)d_in[8];  const float* bv = (const float*)d_in[9];
    const float* Wo = (const float*)d_in[10]; const float* bo = (const float*)d_in[11];
    const float* g1 = (const float*)d_in[12]; const float* be1 = (const float*)d_in[13];
    const float* W1 = (const float*)d_in[14]; const float* bf1 = (const float*)d_in[15];
    const float* W2 = (const float*)d_in[16]; const float* bf2 = (const float*)d_in[17];
    const float* g2 = (const float*)d_in[18]; const float* be2 = (const float*)d_in[19];

    const size_t MB = 1ull << 20;
    char* ws = (char*)d_ws;
    // static region map (time-multiplexed; peak ~145.2 MB)
    ushort_t* WqT = (ushort_t*)(ws);             // [0,2)
    ushort_t* WkT = (ushort_t*)(ws + 2 * MB);    // [2,4)
    ushort_t* WvT = (ushort_t*)(ws + 4 * MB);    // [4,6)
    ushort_t* WoT = (ushort_t*)(ws + 6 * MB);    // [6,8)
    ushort_t* W1T = (ushort_t*)(ws + 8 * MB);    // [8,16)   [F][D]
    ushort_t* W2T = (ushort_t*)(ws + 16 * MB);   // [16,24)  [D][F]
    ushort_t* qin = (ushort_t*)(ws + 24 * MB);   // [24,32)  dead after qkv
    ushort_t* kin = (ushort_t*)(ws + 32 * MB);   // [32,40)  dead after qkv
    ushort_t* vin = (ushort_t*)(ws + 40 * MB);   // [40,48)  dead after qkv
    ushort_t* qb  = (ushort_t*)(ws + 48 * MB);   // [48,56)  dead after QK^T
    ushort_t* kb  = (ushort_t*)(ws + 56 * MB);   // [56,64)  dead after QK^T
    ushort_t* vb  = (ushort_t*)(ws + 64 * MB);   // [64,72)  dead after v-transpose
    ushort_t* vT  = (ushort_t*)(ws + 72 * MB);   // [72,80)  [D][S]
    ushort_t* msc = (ushort_t*)(ws + 80 * MB);   // [80,112) dead after smax3
    ushort_t* hb  = (ushort_t*)(ws + 112 * MB);  // [112,144) dead after h@v
    float*   pmax = (float*)(ws + 144 * MB);
    float*   psum = (float*)(ws + 144 * MB + 512 * 1024);
    float*   cmax = (float*)(ws + 145 * MB);
    float*   cinv = (float*)(ws + 145 * MB + 64 * 1024);
    // reused regions
    ushort_t* pts1  = (ushort_t*)(ws + 80 * MB); // h@v partials 4x8MB over msc
    ushort_t* apb   = (ushort_t*)(ws + 24 * MB); // attn_pre bf16 over qin
    ushort_t* pts2  = (ushort_t*)(ws + 80 * MB); // attn@Wo partials 2x8MB
    float*    attnf = (float*)(ws + 32 * MB);    // attn f32 over kin+vin
    float*    n1f   = (float*)(ws + 48 * MB);    // over qb+kb
    ushort_t* n1b   = (ushort_t*)(ws + 64 * MB); // over vb
    ushort_t* mid   = (ushort_t*)(ws + 112 * MB);// [S][F] bf16 over hb
    ushort_t* pts3  = (ushort_t*)(ws + 80 * MB); // ff partials 4x8MB
    float*    fff   = (float*)(ws + 24 * MB);    // ff f32 over apb+attnf head

    const int S = S_DIM, D = D_DIM, F = F_DIM;

    // 1. weights -> bf16 transposed
    transpose_f32_bf16<<<dim3(D / 32, D / 32), 256, 0, stream>>>(Wq, WqT, D, D);
    transpose_f32_bf16<<<dim3(D / 32, D / 32), 256, 0, stream>>>(Wk, WkT, D, D);
    transpose_f32_bf16<<<dim3(D / 32, D / 32), 256, 0, stream>>>(Wv, WvT, D, D);
    transpose_f32_bf16<<<dim3(D / 32, D / 32), 256, 0, stream>>>(Wo, WoT, D, D);
    transpose_f32_bf16<<<dim3(F / 32, D / 32), 256, 0, stream>>>(W1, W1T, D, F);
    transpose_f32_bf16<<<dim3(D / 32, F / 32), 256, 0, stream>>>(W2, W2T, F, D);

    // 2. activations -> bf16
    cvt_bf16<<<(S * D / 8 + 255) / 256, 256, 0, stream>>>(query, qin, S * D);
    cvt_bf16<<<(S * D / 8 + 255) / 256, 256, 0, stream>>>(key_,  kin, S * D);
    cvt_bf16<<<(S * D / 8 + 255) / 256, 256, 0, stream>>>(value, vin, S * D);

    // 3. batched q,k,v projections (768 blocks = 3/CU)
    qkv_gemm<<<dim3(S / BM, D / BN, 3), 256, 0, stream>>>(
        qin, kin, vin, WqT, WkT, WvT, bq, bk, bv, qb, kb, vb, S, D, D);

    // 4. v^T bf16 [D][S]
    transpose_bf16<<<dim3(D / 32, S / 32), 256, 0, stream>>>(vb, vT, S, D);

    // 5. masked scaled scores: (q @ k^T) * mask / sqrt(D)   (grid 1024)
    gemm_bt<false, false, true, true><<<dim3(S / BM, S / BN), 256, 0, stream>>>(
        qb, kb, nullptr, mask, nullptr, msc, S, S, D, 0.03125f);

    // 6. column softmax
    smax_pass1<<<dim3(S / 256, SM_CH), 256, 0, stream>>>(msc, pmax, psum);
    smax_pass2<<<S / 256, 256, 0, stream>>>(pmax, psum, cmax, cinv);
    smax_pass3<<<(size_t)S * S / 8 / 256, 256, 0, stream>>>(msc, cmax, cinv, hb);

    // 7. attn_pre = h @ v  — 4-way split-K (1024 blocks = 4/CU)
    gemm_bt_sk<<<dim3(S / BM, D / BN, 4), 256, 0, stream>>>(hb, vT, pts1, S, D, S, S / 4);
    reduce_sk<4, false, true><<<S * D / 2048, 256, 0, stream>>>(
        pts1, nullptr, nullptr, apb, (size_t)S * D, D);

    // 8. attn = attn_pre @ Wo + bo — 2-way split-K (512 blocks = 2/CU)
    gemm_bt_sk<<<dim3(S / BM, D / BN, 2), 256, 0, stream>>>(apb, WoT, pts2, S, D, D, D / 2);
    reduce_sk<2, true, false><<<S * D / 2048, 256, 0, stream>>>(
        pts2, bo, attnf, nullptr, (size_t)S * D, D);

    // 9. n1 = LN(attn + query)
    add_ln<true, true><<<S, 256, 0, stream>>>(attnf, query, g1, be1, n1f, n1b);

    // 10. mid = relu(n1 @ W1 + bf1)  (grid 1024)
    gemm_bt<true, true, false, true><<<dim3(S / BM, F / BN), 256, 0, stream>>>(
        n1b, W1T, bf1, nullptr, nullptr, mid, S, F, D, 1.f);

    // 11. ff = mid @ W2 + bf2 — 4-way split-K (1024 blocks = 4/CU)
    gemm_bt_sk<<<dim3(S / BM, D / BN, 4), 256, 0, stream>>>(mid, W2T, pts3, S, D, F, F / 4);
    reduce_sk<4, true, false><<<S * D / 2048, 256, 0, stream>>>(
        pts3, bf2, fff, nullptr, (size_t)S * D, D);

    // 12. out = LN(ff + n1)
    add_ln<true, false><<<S, 256, 0, stream>>>(fff, n1f, g2, be2, (float*)d_out, nullptr);
}